// Round 3
// baseline (407.369 us; speedup 1.0000x reference)
//
#include <hip/hip_runtime.h>
#include <math.h>

// Sizes (fixed by the reference)
#define BATCH 16384
#define K_DIM 3072
#define KS    3        // split-K factor
#define KSLICE 1024    // K per block (K_DIM / KS)
#define BM    64       // rows per gemm block
#define NITER 16       // KSLICE / 64

typedef float  f32x4  __attribute__((ext_vector_type(4)));
typedef __bf16 bf16x8 __attribute__((ext_vector_type(8)));
typedef unsigned int u32x4 __attribute__((ext_vector_type(4)));
typedef unsigned int u32x2 __attribute__((ext_vector_type(2)));

__device__ __forceinline__ unsigned short f2bf(float f) {
  union { float f; unsigned u; } v; v.f = f;
  unsigned u = v.u + 0x7fffu + ((v.u >> 16) & 1u);   // RNE
  return (unsigned short)(u >> 16);
}

// ---------------- kernel 1: w1 fp32 -> bf16, and w2 -> w2t (i-major) ----------------
__global__ void cvt_kernel(const float* __restrict__ w1, unsigned short* __restrict__ o,
                           const float* __restrict__ w2, float* __restrict__ w2t) {
  if (blockIdx.x < 384) {
    int i = blockIdx.x * 256 + threadIdx.x;          // 98304 float4s
    f32x4 v = ((const f32x4*)w1)[i];
    u32x2 p = { (unsigned)f2bf(v.x) | ((unsigned)f2bf(v.y) << 16),
                (unsigned)f2bf(v.z) | ((unsigned)f2bf(v.w) << 16) };
    ((u32x2*)o)[i] = p;
  } else {
    // one block: transpose w2 (8,32,30) -> w2t[e][i*32+o]
    for (int j = threadIdx.x; j < 7680; j += 256) {
      int e = j / 960; int r = j - e * 960; int oo = r / 30; int ii = r - oo * 30;
      w2t[e * 960 + ii * 32 + oo] = w2[j];
    }
  }
}

// ---------------- kernel 2: split-K GEMM, fp32 partials ----------------
// grid = 256 m-blocks x KS splits = 768 blocks, 256 threads, 3 blocks/CU.
// Each block: 64 rows x 128 outs x 1024 K-slice -> partial[ks][row][128].
__global__ __launch_bounds__(256, 3) void gemm_partial_kernel(
    const float* __restrict__ x, const unsigned short* __restrict__ w1bf,
    float* __restrict__ partial) {
  __shared__ __align__(16) unsigned short xs[64 * 72];    //  9216 B (pad-72 rows)
  __shared__ __align__(16) unsigned short wsd[128 * 72];  // 18432 B

  const int tid = threadIdx.x;
  const int bm  = blockIdx.x / KS;
  const int ksl = blockIdx.x - bm * KS;
  const int m0  = bm * BM;
  const size_t k0 = (size_t)ksl * KSLICE;

  // staging map: id = p*256 + tid -> row = id>>4, 8B-chunk c = tid&15
  const int srow = tid >> 4;       // 0..15 base row (within 16-row group p)
  const int sc   = tid & 15;       // 8-byte chunk (4 elements)
  const float*          gx = x    + (size_t)(m0 + srow) * K_DIM + k0 + sc * 4;
  const unsigned short* gw = w1bf + (size_t)srow * K_DIM + k0 + sc * 4;
  const int sxo = srow * 72 + sc * 4;   // shorts

  // frag addressing
  const int lane = tid & 63, wid = tid >> 6;
  const int m16 = lane & 15, q = lane >> 4;
  const int arow = (wid & 1) * 32;          // wave's 32-row half
  const int bcol = (wid >> 1) * 64;         // wave's 64-col half

  f32x4 acc[2][4];
#pragma unroll
  for (int i = 0; i < 2; ++i)
#pragma unroll
    for (int j = 0; j < 4; ++j) acc[i][j] = (f32x4){0.f, 0.f, 0.f, 0.f};

  // prefetch kt=0 into registers
  f32x4 xv[4];
  u32x2 wv[8];
#pragma unroll
  for (int p = 0; p < 4; ++p) xv[p] = *(const f32x4*)(gx + (size_t)p * 16 * K_DIM);
#pragma unroll
  for (int p = 0; p < 8; ++p) wv[p] = *(const u32x2*)(gw + (size_t)p * 16 * K_DIM);

  for (int kt = 0; kt < NITER; ++kt) {
    __syncthreads();  // previous iteration's ds_reads complete
    // commit staged tile to LDS (bf16 cvt for x)
#pragma unroll
    for (int p = 0; p < 4; ++p) {
      u32x2 pk = { (unsigned)f2bf(xv[p].x) | ((unsigned)f2bf(xv[p].y) << 16),
                   (unsigned)f2bf(xv[p].z) | ((unsigned)f2bf(xv[p].w) << 16) };
      *(u32x2*)&xs[sxo + p * 16 * 72] = pk;
    }
#pragma unroll
    for (int p = 0; p < 8; ++p)
      *(u32x2*)&wsd[sxo + p * 16 * 72] = wv[p];
    __syncthreads();  // tile visible
    if (kt < NITER - 1) {  // prefetch next tile; overlaps MFMA
      const size_t ko = (size_t)(kt + 1) * 64;
#pragma unroll
      for (int p = 0; p < 4; ++p) xv[p] = *(const f32x4*)(gx + (size_t)p * 16 * K_DIM + ko);
#pragma unroll
      for (int p = 0; p < 8; ++p) wv[p] = *(const u32x2*)(gw + (size_t)p * 16 * K_DIM + ko);
    }
#pragma unroll
    for (int ks2 = 0; ks2 < 2; ++ks2) {
      bf16x8 af[2];
#pragma unroll
      for (int i = 0; i < 2; ++i)
        af[i] = *(const bf16x8*)&xs[(arow + i * 16 + m16) * 72 + ks2 * 32 + q * 8];
#pragma unroll
      for (int j = 0; j < 4; ++j) {
        bf16x8 bf = *(const bf16x8*)&wsd[(bcol + j * 16 + m16) * 72 + ks2 * 32 + q * 8];
#pragma unroll
        for (int i = 0; i < 2; ++i)
          acc[i][j] = __builtin_amdgcn_mfma_f32_16x16x32_bf16(af[i], bf, acc[i][j], 0, 0, 0);
      }
    }
  }

  // write fp32 partials: D row(M)=q*4+r, col(N)=m16
  float* pb = partial + (size_t)ksl * (BATCH * 128);
#pragma unroll
  for (int i = 0; i < 2; ++i)
#pragma unroll
    for (int j = 0; j < 4; ++j)
#pragma unroll
      for (int r = 0; r < 4; ++r)
        pb[(size_t)(m0 + arow + i * 16 + q * 4 + r) * 128 + bcol + j * 16 + m16] = acc[i][j][r];
}

// ---------------- kernel 3: reduce partials + router + MLP + probe ----------------
// 512 blocks x 256 threads; block = 32 rows, thread = (row, expert)
__global__ __launch_bounds__(256, 4) void moe_tail_kernel(
    const float* __restrict__ x, const float* __restrict__ partial,
    const float* __restrict__ b1, const float* __restrict__ w2t,
    const float* __restrict__ b2, const float* __restrict__ w3,
    const float* __restrict__ b3, const float* __restrict__ psqt,
    const float* __restrict__ st, const float* __restrict__ rw,
    const float* __restrict__ rb, float* __restrict__ out,
    float* __restrict__ accs) {
  __shared__ float rws_s[512];
  __shared__ int   hist_s[8];
  __shared__ float zsum_s, psum_s;

  const int tid = threadIdx.x;
  const int bm  = blockIdx.x;
  rws_s[tid] = rw[tid];
  rws_s[tid + 256] = rw[tid + 256];
  if (tid < 8) hist_s[tid] = 0;
  if (tid == 0) { zsum_s = 0.f; psum_s = 0.f; }
  __syncthreads();

  const int r = tid >> 3, e = tid & 7;
  const int bg = bm * 32 + r;
  const int lane = tid & 63, wid = tid >> 6;

  // l1c row slice for this (row, expert): sum of KS partials + b1
  float a[16];
  {
    const size_t off = (size_t)bg * 128 + e * 16;
#pragma unroll
    for (int j4 = 0; j4 < 4; ++j4) {
      f32x4 s = *(const f32x4*)(partial + off + j4 * 4);
      s = s + *(const f32x4*)(partial + (size_t)BATCH * 128 + off + j4 * 4);
      s = s + *(const f32x4*)(partial + (size_t)2 * BATCH * 128 + off + j4 * 4);
      f32x4 bq = *(const f32x4*)(b1 + e * 16 + j4 * 4);
      s = s + bq;
      a[j4 * 4 + 0] = s.x; a[j4 * 4 + 1] = s.y; a[j4 * 4 + 2] = s.z; a[j4 * 4 + 3] = s.w;
    }
  }

  // ---- router (fp64 for argmax stability), 8 expert-lanes per row ----
  float logp_own; int cand;
  {
    const float* xrow = x + (size_t)bg * K_DIM;
    double l0 = (double)rb[e], l1 = 0.0;
#pragma unroll
    for (int c = 0; c < 32; c += 2) {
      l0 = fma((double)xrow[c],     (double)rws_s[e * 64 + c],     l0);
      l1 = fma((double)xrow[c + 1], (double)rws_s[e * 64 + c + 1], l1);
    }
#pragma unroll
    for (int c = 0; c < 32; c += 2) {
      l0 = fma((double)xrow[1536 + c],     (double)rws_s[e * 64 + 32 + c],     l0);
      l1 = fma((double)xrow[1536 + c + 1], (double)rws_s[e * 64 + 32 + c + 1], l1);
    }
    double l = l0 + l1;
    double mx = l;
    mx = fmax(mx, __shfl_xor(mx, 1));
    mx = fmax(mx, __shfl_xor(mx, 2));
    mx = fmax(mx, __shfl_xor(mx, 4));
    int cd = (l == mx) ? e : 8;          // first-max tiebreak like argmax
    cd = min(cd, __shfl_xor(cd, 1));
    cd = min(cd, __shfl_xor(cd, 2));
    cd = min(cd, __shfl_xor(cd, 4));
    cand = cd;
    double s = exp(l - mx);
    s += __shfl_xor(s, 1); s += __shfl_xor(s, 2); s += __shfl_xor(s, 4);
    double lse = mx + log(s);
    logp_own = (float)(l - lse);
    if (e == 0) atomicAdd(&zsum_s, (float)(lse * lse));
    if (e == cd) atomicAdd(&hist_s[cd], 1);
  }

  // ---- MLP layers 2,3 ----
  float h[30];
#pragma unroll
  for (int j = 0; j < 15; ++j) {
    float v = a[j];
    h[j]      = fminf(fmaxf(v * v * (255.0f / 256.0f), 0.f), 1.f);
    h[15 + j] = fminf(fmaxf(v, 0.f), 1.f);
  }

  float acc2[32];
  const f32x4* b2v = (const f32x4*)(b2 + e * 32);
#pragma unroll
  for (int o4 = 0; o4 < 8; ++o4) {
    f32x4 bq = b2v[o4];
    acc2[o4 * 4 + 0] = bq.x; acc2[o4 * 4 + 1] = bq.y;
    acc2[o4 * 4 + 2] = bq.z; acc2[o4 * 4 + 3] = bq.w;
  }
  const f32x4* wrow = (const f32x4*)(w2t + e * 960);
#pragma unroll
  for (int i = 0; i < 30; ++i) {
    float hv = h[i];
#pragma unroll
    for (int o4 = 0; o4 < 8; ++o4) {
      f32x4 wq = wrow[i * 8 + o4];
      acc2[o4 * 4 + 0] += hv * wq.x;
      acc2[o4 * 4 + 1] += hv * wq.y;
      acc2[o4 * 4 + 2] += hv * wq.z;
      acc2[o4 * 4 + 3] += hv * wq.w;
    }
  }

  float outv = b3[e] + a[15];  // b3 + skip
  const f32x4* w3v = (const f32x4*)(w3 + e * 32);
#pragma unroll
  for (int o4 = 0; o4 < 8; ++o4) {
    f32x4 wq = w3v[o4];
#pragma unroll
    for (int k = 0; k < 4; ++k) {
      float l2v = fminf(fmaxf(acc2[o4 * 4 + k], 0.f), 1.f);
      outv += l2v * ((const float*)&wq)[k];
    }
  }

  // ---- probe softmax over the 8 experts ----
  float eo  = (outv + psqt[bg]) * 600.0f;
  float dd  = eo - st[bg];
  float err = dd * dd;
  float mn = err;
  mn = fminf(mn, __shfl_xor(mn, 1));
  mn = fminf(mn, __shfl_xor(mn, 2));
  mn = fminf(mn, __shfl_xor(mn, 4));
  float wexp = expf(-(err - mn));
  float ssum = wexp;
  ssum += __shfl_xor(ssum, 1); ssum += __shfl_xor(ssum, 2); ssum += __shfl_xor(ssum, 4);
  float pt  = wexp / ssum;
  float lpt = logf(fmaxf(pt, 1e-30f));
  float term = pt * (lpt - logp_own);
  term += __shfl_xor(term, 1); term += __shfl_xor(term, 2); term += __shfl_xor(term, 4);
  float c1 = (e == 0) ? term : 0.f;
  c1 += __shfl_xor(c1, 8); c1 += __shfl_xor(c1, 16); c1 += __shfl_xor(c1, 32);
  if (lane == 0) atomicAdd(&psum_s, c1);

  if (e == cand) out[bg] = outv;  // gating multiplier is exactly 1.0 in fwd

  __syncthreads();
  if (tid == 0) {
    atomicAdd(&accs[8], zsum_s);
    atomicAdd(&accs[9], psum_s);
  }
  if (tid < 8) atomicAdd(&accs[tid], (float)hist_s[tid]);
}

// ---------------- kernel 4: finalize scalar ----------------
__global__ void finalize_kernel(const float* __restrict__ accs, float* __restrict__ out) {
  if (threadIdx.x == 0) {
    float fsum = 0.f;
    for (int e = 0; e < 8; ++e) {
      float frac = accs[e] * (1.0f / 16384.0f);
      float f = fmaxf(0.05f - frac, 0.f);
      float c = fmaxf(frac - 0.5f, 0.f);
      fsum += f * f + c * c;
    }
    float aux   = fsum * 0.125f;             // floor_loss + cap_loss (each mean over E)
    float z     = accs[8] * (1.0f / 16384.0f);
    float probe = accs[9] * (1.0f / 16384.0f);
    out[BATCH] = 0.01f * aux + 0.001f * z + 0.01f * probe;
  }
}

extern "C" void kernel_launch(void* const* d_in, const int* in_sizes, int n_in,
                              void* d_out, int out_size, void* d_ws, size_t ws_size,
                              hipStream_t stream) {
  const float* x    = (const float*)d_in[0];
  // d_in[1] = ls_indices: unused (TEACHER_ALPHA == 0)
  const float* psqt = (const float*)d_in[2];
  const float* st   = (const float*)d_in[3];
  const float* rw   = (const float*)d_in[4];
  const float* rb   = (const float*)d_in[5];
  const float* w1   = (const float*)d_in[6];
  const float* b1   = (const float*)d_in[7];
  const float* w2   = (const float*)d_in[8];
  const float* b2   = (const float*)d_in[9];
  const float* w3   = (const float*)d_in[10];
  const float* b3   = (const float*)d_in[11];
  float* out = (float*)d_out;

  unsigned short* w1bf = (unsigned short*)d_ws;                      // 786432 B
  float* w2t     = (float*)((char*)d_ws + 786432);                   // 30720 B
  float* accs    = (float*)((char*)d_ws + 786432 + 30720);           // 64 B
  float* partial = (float*)((char*)d_ws + 1048576);                  // 3*16384*128*4 B

  hipMemsetAsync(accs, 0, 16 * sizeof(float), stream);
  cvt_kernel<<<385, 256, 0, stream>>>(w1, w1bf, w2, w2t);
  gemm_partial_kernel<<<768, 256, 0, stream>>>(x, w1bf, partial);
  moe_tail_kernel<<<512, 256, 0, stream>>>(x, partial, b1, w2t, b2, w3, b3,
                                           psqt, st, rw, rb, out, accs);
  finalize_kernel<<<1, 1, 0, stream>>>(accs, out);
}